// Round 1
// baseline (29832.062 us; speedup 1.0000x reference)
//
#include <hip/hip_runtime.h>
#include <cmath>

#define DD 128

__device__ __forceinline__ float sigmoid_f(float x) { return 1.0f / (1.0f + __expf(-x)); }
__device__ __forceinline__ float tanh_f(float x) {
  float e = __expf(2.0f * x);
  return 1.0f - 2.0f / (e + 1.0f);
}

// C[N,128] = A[N,128] @ W^T + b   (W is [128,128] row-major: W[j][k])
__global__ __launch_bounds__(256) void msg_gemm(
    const float* __restrict__ A, const float* __restrict__ W,
    const float* __restrict__ b, float* __restrict__ C, int N)
{
  __shared__ float sW[DD * 33];  // [j][kk] chunk, stride 33 -> conflict-free
  const int tid = threadIdx.x;
  const int jj = tid & 31;
  const int rslot = tid >> 5;
  const int rowBase = blockIdx.x * 64;

  float acc[8][4];
#pragma unroll
  for (int i = 0; i < 8; ++i)
#pragma unroll
    for (int g = 0; g < 4; ++g) acc[i][g] = 0.0f;

  int rows[8];
#pragma unroll
  for (int i = 0; i < 8; ++i) {
    int r = rowBase + rslot * 8 + i;
    rows[i] = (r < N) ? r : (N - 1);
  }

  for (int k0 = 0; k0 < DD; k0 += 32) {
    __syncthreads();
    for (int t = tid; t < DD * 32; t += 256) {
      int j = t >> 5, kk = t & 31;
      sW[j * 33 + kk] = W[j * DD + k0 + kk];
    }
    __syncthreads();
#pragma unroll
    for (int kk4 = 0; kk4 < 32; kk4 += 4) {
      float4 a4[8];
#pragma unroll
      for (int i = 0; i < 8; ++i)
        a4[i] = *(const float4*)(A + (size_t)rows[i] * DD + k0 + kk4);
#pragma unroll
      for (int q = 0; q < 4; ++q) {
        float wv[4];
#pragma unroll
        for (int g = 0; g < 4; ++g) wv[g] = sW[(jj + 32 * g) * 33 + kk4 + q];
#pragma unroll
        for (int i = 0; i < 8; ++i) {
          float av = (q == 0) ? a4[i].x : (q == 1) ? a4[i].y : (q == 2) ? a4[i].z : a4[i].w;
#pragma unroll
          for (int g = 0; g < 4; ++g) acc[i][g] = fmaf(av, wv[g], acc[i][g]);
        }
      }
    }
  }
  float bv[4];
#pragma unroll
  for (int g = 0; g < 4; ++g) bv[g] = b[jj + 32 * g];
#pragma unroll
  for (int i = 0; i < 8; ++i) {
    int r = rowBase + rslot * 8 + i;
    if (r < N) {
#pragma unroll
      for (int g = 0; g < 4; ++g)
        C[(size_t)r * DD + jj + 32 * g] = acc[i][g] + bv[g];
    }
  }
}

// Fused GRU: for 32 output cols (blockIdx.y) x 64 rows (blockIdx.x),
// compute 6 dot-products (r/z/n from agg@Wih^T and h@Whh^T) and gate.
__global__ __launch_bounds__(256) void gru_fused(
    const float* __restrict__ Agg, const float* __restrict__ H,
    const float* __restrict__ Wih, const float* __restrict__ Whh,
    const float* __restrict__ bih, const float* __restrict__ bhh,
    float* __restrict__ Hout, int N, int do_relu)
{
  __shared__ float sW[192 * 33];  // [g*32+jj][kk], g<3: Wih, g>=3: Whh
  const int tid = threadIdx.x;
  const int jj = tid & 31;
  const int rslot = tid >> 5;
  const int rowBase = blockIdx.x * 64;
  const int j0 = blockIdx.y * 32;
  const int c = j0 + jj;

  float acc[6][8];
#pragma unroll
  for (int g = 0; g < 6; ++g)
#pragma unroll
    for (int i = 0; i < 8; ++i) acc[g][i] = 0.0f;

  int rows[8];
#pragma unroll
  for (int i = 0; i < 8; ++i) {
    int r = rowBase + rslot * 8 + i;
    rows[i] = (r < N) ? r : (N - 1);
  }

  for (int k0 = 0; k0 < DD; k0 += 32) {
    __syncthreads();
    for (int t = tid; t < 192 * 32; t += 256) {
      int w = t >> 5, kk = t & 31;
      float v;
      if (w < 96) {
        int row = (w >> 5) * 128 + j0 + (w & 31);
        v = Wih[row * DD + k0 + kk];
      } else {
        int w2 = w - 96;
        int row = (w2 >> 5) * 128 + j0 + (w2 & 31);
        v = Whh[row * DD + k0 + kk];
      }
      sW[w * 33 + kk] = v;
    }
    __syncthreads();
#pragma unroll
    for (int kk4 = 0; kk4 < 32; kk4 += 4) {
      float4 a4[8], h4[8];
#pragma unroll
      for (int i = 0; i < 8; ++i) {
        a4[i] = *(const float4*)(Agg + (size_t)rows[i] * DD + k0 + kk4);
        h4[i] = *(const float4*)(H + (size_t)rows[i] * DD + k0 + kk4);
      }
#pragma unroll
      for (int q = 0; q < 4; ++q) {
        float wv[6];
#pragma unroll
        for (int g = 0; g < 6; ++g) wv[g] = sW[(g * 32 + jj) * 33 + kk4 + q];
#pragma unroll
        for (int i = 0; i < 8; ++i) {
          float av = (q == 0) ? a4[i].x : (q == 1) ? a4[i].y : (q == 2) ? a4[i].z : a4[i].w;
          float hv = (q == 0) ? h4[i].x : (q == 1) ? h4[i].y : (q == 2) ? h4[i].z : h4[i].w;
#pragma unroll
          for (int g = 0; g < 3; ++g) acc[g][i] = fmaf(av, wv[g], acc[g][i]);
#pragma unroll
          for (int g = 3; g < 6; ++g) acc[g][i] = fmaf(hv, wv[g], acc[g][i]);
        }
      }
    }
  }

  const float bir = bih[c], biz = bih[128 + c], bin = bih[256 + c];
  const float bhr = bhh[c], bhz = bhh[128 + c], bhn = bhh[256 + c];
#pragma unroll
  for (int i = 0; i < 8; ++i) {
    int r = rowBase + rslot * 8 + i;
    if (r < N) {
      float ir = acc[0][i] + bir, iz = acc[1][i] + biz, in = acc[2][i] + bin;
      float hr = acc[3][i] + bhr, hz = acc[4][i] + bhz, hn = acc[5][i] + bhn;
      float rg = sigmoid_f(ir + hr);
      float zg = sigmoid_f(iz + hz);
      float ng = tanh_f(in + rg * hn);
      float hold = H[(size_t)r * DD + c];
      float out = (1.0f - zg) * ng + zg * hold;
      if (do_relu) out = fmaxf(out, 0.0f);
      Hout[(size_t)r * DD + c] = out;
    }
  }
}

// agg[dst[e]] += m[src[e]] for all edges; one thread per (edge, 4-float chunk)
__global__ __launch_bounds__(256) void scatter_add_k(
    const float* __restrict__ m, const int* __restrict__ src,
    const int* __restrict__ dst, float* __restrict__ agg, int E)
{
  long long total = (long long)E * 32;
  long long idx = (long long)blockIdx.x * blockDim.x + threadIdx.x;
  long long stride = (long long)gridDim.x * blockDim.x;
  for (; idx < total; idx += stride) {
    int e = (int)(idx >> 5);
    int cc = ((int)idx & 31) << 2;
    int s = src[e], d = dst[e];
    float4 v = *(const float4*)(m + (size_t)s * DD + cc);
    float* p = agg + (size_t)d * DD + cc;
    unsafeAtomicAdd(p + 0, v.x);
    unsafeAtomicAdd(p + 1, v.y);
    unsafeAtomicAdd(p + 2, v.z);
    unsafeAtomicAdd(p + 3, v.w);
  }
}

// out[c] = mean over rows of H[:, c]; out must be zeroed first
__global__ __launch_bounds__(256) void col_mean(
    const float* __restrict__ H, float* __restrict__ out, int N)
{
  __shared__ float s[256];
  int c = threadIdx.x & 127;
  int rg = threadIdx.x >> 7;
  float acc = 0.0f;
  for (int r = blockIdx.x * 2 + rg; r < N; r += gridDim.x * 2)
    acc += H[(size_t)r * DD + c];
  s[threadIdx.x] = acc;
  __syncthreads();
  if (threadIdx.x < 128) {
    float v = (s[threadIdx.x] + s[threadIdx.x + 128]) * (1.0f / (float)N);
    unsafeAtomicAdd(out + c, v);
  }
}

extern "C" void kernel_launch(void* const* d_in, const int* in_sizes, int n_in,
                              void* d_out, int out_size, void* d_ws, size_t ws_size,
                              hipStream_t stream) {
  const float* in_feat = (const float*)d_in[0];
  const int* src = (const int*)d_in[1];
  const int* dst = (const int*)d_in[2];
  const float* W[2]   = {(const float*)d_in[3], (const float*)d_in[9]};
  const float* bb[2]  = {(const float*)d_in[4], (const float*)d_in[10]};
  const float* Wih[2] = {(const float*)d_in[5], (const float*)d_in[11]};
  const float* Whh[2] = {(const float*)d_in[6], (const float*)d_in[12]};
  const float* bih[2] = {(const float*)d_in[7], (const float*)d_in[13]};
  const float* bhh[2] = {(const float*)d_in[8], (const float*)d_in[14]};
  const int N = in_sizes[0] / DD;
  const int E = in_sizes[1];

  float* ws = (float*)d_ws;
  const size_t nd = (size_t)N * DD;
  float* hA  = ws;
  float* hB  = hA + nd;
  float* m   = hB + nd;
  float* agg = m + nd;

  hipMemcpyAsync(hA, in_feat, nd * sizeof(float), hipMemcpyDeviceToDevice, stream);

  float* hcur = hA;
  float* hnxt = hB;
  const int mblocks = (N + 63) / 64;

  for (int layer = 0; layer < 2; ++layer) {
    for (int step_i = 0; step_i < 8; ++step_i) {
      msg_gemm<<<mblocks, 256, 0, stream>>>(hcur, W[layer], bb[layer], m, N);
      hipMemsetAsync(agg, 0, nd * sizeof(float), stream);
      scatter_add_k<<<2048, 256, 0, stream>>>(m, src, dst, agg, E);
      int do_relu = (layer == 0 && step_i == 7) ? 1 : 0;
      gru_fused<<<dim3(mblocks, 4), 256, 0, stream>>>(
          agg, hcur, Wih[layer], Whh[layer], bih[layer], bhh[layer],
          hnxt, N, do_relu);
      float* t = hcur; hcur = hnxt; hnxt = t;
    }
  }

  hipMemsetAsync(d_out, 0, DD * sizeof(float), stream);
  col_mean<<<256, 256, 0, stream>>>(hcur, (float*)d_out, N);
}

// Round 2
// 8592.182 us; speedup vs baseline: 3.4720x; 3.4720x over previous
//
#include <hip/hip_runtime.h>
#include <cmath>

#define DD 128

__device__ __forceinline__ float sigmoid_f(float x) { return 1.0f / (1.0f + __expf(-x)); }
__device__ __forceinline__ float tanh_f(float x) {
  float e = __expf(2.0f * x);
  return 1.0f - 2.0f / (e + 1.0f);
}

// ---------------- CSR build ----------------
__global__ __launch_bounds__(256) void deg_count(const int* __restrict__ dst,
                                                 int* __restrict__ deg, int E) {
  int e = blockIdx.x * blockDim.x + threadIdx.x;
  if (e < E) atomicAdd(&deg[dst[e]], 1);
}

__global__ __launch_bounds__(1024) void scan_deg(const int* __restrict__ deg,
                                                 int* __restrict__ ofs,
                                                 int* __restrict__ cur, int N) {
  __shared__ int part[1024];
  const int t = threadIdx.x;
  const int chunk = (N + 1023) / 1024;
  const int beg = t * chunk;
  const int end = min(beg + chunk, N);
  int s = 0;
  for (int i = beg; i < end; ++i) s += deg[i];
  part[t] = s;
  __syncthreads();
  if (t == 0) {
    int run = 0;
    for (int i = 0; i < 1024; ++i) { int v = part[i]; part[i] = run; run += v; }
    ofs[N] = run;
  }
  __syncthreads();
  int run = part[t];
  for (int i = beg; i < end; ++i) { ofs[i] = run; cur[i] = run; run += deg[i]; }
}

__global__ __launch_bounds__(256) void fill_csr(const int* __restrict__ src,
                                                const int* __restrict__ dst,
                                                int* __restrict__ cur,
                                                int* __restrict__ eidx, int E) {
  int e = blockIdx.x * blockDim.x + threadIdx.x;
  if (e < E) {
    int p = atomicAdd(&cur[dst[e]], 1);
    eidx[p] = src[e];
  }
}

// ---------------- weight fusion: Wf = Wih @ W  [384,128], u = Wih @ b [384] ----------------
__global__ __launch_bounds__(128) void fuse_w(const float* __restrict__ Wih,
                                              const float* __restrict__ W,
                                              float* __restrict__ Wf) {
  int r = blockIdx.x;          // 0..383
  int k = threadIdx.x;         // 0..127
  float acc = 0.0f;
  for (int j = 0; j < DD; ++j) acc = fmaf(Wih[r * DD + j], W[j * DD + k], acc);
  Wf[r * DD + k] = acc;
}

__global__ __launch_bounds__(128) void fuse_u(const float* __restrict__ Wih,
                                              const float* __restrict__ b,
                                              float* __restrict__ u) {
  int r = blockIdx.x * 128 + threadIdx.x;
  if (r < 3 * DD) {
    float acc = 0.0f;
    for (int j = 0; j < DD; ++j) acc = fmaf(Wih[r * DD + j], b[j], acc);
    u[r] = acc;
  }
}

// ---------------- aggregation: agg[n] = sum_{e in CSR[n]} h[eidx[e]] ----------------
__global__ __launch_bounds__(256) void gather_h(const float* __restrict__ h,
                                                const int* __restrict__ ofs,
                                                const int* __restrict__ eidx,
                                                float* __restrict__ agg, int N) {
  int node = blockIdx.x * 4 + (threadIdx.x >> 6);
  if (node >= N) return;
  int lane = threadIdx.x & 63;
  int beg = ofs[node], end = ofs[node + 1];
  float2 acc0 = {0.0f, 0.0f}, acc1 = {0.0f, 0.0f};
  int e = beg;
  for (; e + 1 < end; e += 2) {
    int s0 = eidx[e], s1 = eidx[e + 1];
    float2 v0 = *(const float2*)(h + (size_t)s0 * DD + lane * 2);
    float2 v1 = *(const float2*)(h + (size_t)s1 * DD + lane * 2);
    acc0.x += v0.x; acc0.y += v0.y;
    acc1.x += v1.x; acc1.y += v1.y;
  }
  if (e < end) {
    int s = eidx[e];
    float2 v = *(const float2*)(h + (size_t)s * DD + lane * 2);
    acc0.x += v.x; acc0.y += v.y;
  }
  float2 r;
  r.x = acc0.x + acc1.x;
  r.y = acc0.y + acc1.y;
  *(float2*)(agg + (size_t)node * DD + lane * 2) = r;
}

// ---------------- fused GRU ----------------
// gi = Agg @ Wf^T + bih + deg*u ; gh = H @ Whh^T + bhh ; gate + optional relu
__global__ __launch_bounds__(256) void gru_fused(
    const float* __restrict__ Agg, const float* __restrict__ H,
    const float* __restrict__ Wf, const float* __restrict__ Whh,
    const float* __restrict__ bih, const float* __restrict__ bhh,
    const float* __restrict__ u, const int* __restrict__ deg,
    float* __restrict__ Hout, int N, int do_relu)
{
  __shared__ float sW[192 * 33];  // [g*32+jj][kk], g<3: Wf, g>=3: Whh
  const int tid = threadIdx.x;
  const int jj = tid & 31;
  const int rslot = tid >> 5;
  const int rowBase = blockIdx.x * 64;
  const int j0 = blockIdx.y * 32;
  const int c = j0 + jj;

  float acc[6][8];
#pragma unroll
  for (int g = 0; g < 6; ++g)
#pragma unroll
    for (int i = 0; i < 8; ++i) acc[g][i] = 0.0f;

  int rows[8];
#pragma unroll
  for (int i = 0; i < 8; ++i) {
    int r = rowBase + rslot * 8 + i;
    rows[i] = (r < N) ? r : (N - 1);
  }

  for (int k0 = 0; k0 < DD; k0 += 32) {
    __syncthreads();
    for (int t = tid; t < 192 * 32; t += 256) {
      int w = t >> 5, kk = t & 31;
      float v;
      if (w < 96) {
        int row = (w >> 5) * DD + j0 + (w & 31);
        v = Wf[row * DD + k0 + kk];
      } else {
        int w2 = w - 96;
        int row = (w2 >> 5) * DD + j0 + (w2 & 31);
        v = Whh[row * DD + k0 + kk];
      }
      sW[w * 33 + kk] = v;
    }
    __syncthreads();
#pragma unroll
    for (int kk4 = 0; kk4 < 32; kk4 += 4) {
      float4 a4[8], h4[8];
#pragma unroll
      for (int i = 0; i < 8; ++i) {
        a4[i] = *(const float4*)(Agg + (size_t)rows[i] * DD + k0 + kk4);
        h4[i] = *(const float4*)(H + (size_t)rows[i] * DD + k0 + kk4);
      }
#pragma unroll
      for (int q = 0; q < 4; ++q) {
        float wv[6];
#pragma unroll
        for (int g = 0; g < 6; ++g) wv[g] = sW[(g * 32 + jj) * 33 + kk4 + q];
#pragma unroll
        for (int i = 0; i < 8; ++i) {
          float av = (q == 0) ? a4[i].x : (q == 1) ? a4[i].y : (q == 2) ? a4[i].z : a4[i].w;
          float hv = (q == 0) ? h4[i].x : (q == 1) ? h4[i].y : (q == 2) ? h4[i].z : h4[i].w;
#pragma unroll
          for (int g = 0; g < 3; ++g) acc[g][i] = fmaf(av, wv[g], acc[g][i]);
#pragma unroll
          for (int g = 3; g < 6; ++g) acc[g][i] = fmaf(hv, wv[g], acc[g][i]);
        }
      }
    }
  }

  const float bir = bih[c], biz = bih[DD + c], bin = bih[2 * DD + c];
  const float bhr = bhh[c], bhz = bhh[DD + c], bhn = bhh[2 * DD + c];
  const float ur = u[c], uz = u[DD + c], un = u[2 * DD + c];
#pragma unroll
  for (int i = 0; i < 8; ++i) {
    int r = rowBase + rslot * 8 + i;
    if (r < N) {
      float dg = (float)deg[r];
      float ir = acc[0][i] + bir + dg * ur;
      float iz = acc[1][i] + biz + dg * uz;
      float in = acc[2][i] + bin + dg * un;
      float hr = acc[3][i] + bhr, hz = acc[4][i] + bhz, hn = acc[5][i] + bhn;
      float rg = sigmoid_f(ir + hr);
      float zg = sigmoid_f(iz + hz);
      float ng = tanh_f(in + rg * hn);
      float hold = H[(size_t)r * DD + c];
      float out = (1.0f - zg) * ng + zg * hold;
      if (do_relu) out = fmaxf(out, 0.0f);
      Hout[(size_t)r * DD + c] = out;
    }
  }
}

// out[c] = mean over rows of H[:, c]; out must be zeroed first
__global__ __launch_bounds__(256) void col_mean(
    const float* __restrict__ H, float* __restrict__ out, int N)
{
  __shared__ float s[256];
  int c = threadIdx.x & 127;
  int rg = threadIdx.x >> 7;
  float acc = 0.0f;
  for (int r = blockIdx.x * 2 + rg; r < N; r += gridDim.x * 2)
    acc += H[(size_t)r * DD + c];
  s[threadIdx.x] = acc;
  __syncthreads();
  if (threadIdx.x < 128) {
    float v = (s[threadIdx.x] + s[threadIdx.x + 128]) * (1.0f / (float)N);
    unsafeAtomicAdd(out + c, v);
  }
}

extern "C" void kernel_launch(void* const* d_in, const int* in_sizes, int n_in,
                              void* d_out, int out_size, void* d_ws, size_t ws_size,
                              hipStream_t stream) {
  const float* in_feat = (const float*)d_in[0];
  const int* src = (const int*)d_in[1];
  const int* dst = (const int*)d_in[2];
  const float* W[2]   = {(const float*)d_in[3], (const float*)d_in[9]};
  const float* bb[2]  = {(const float*)d_in[4], (const float*)d_in[10]};
  const float* Wih[2] = {(const float*)d_in[5], (const float*)d_in[11]};
  const float* Whh[2] = {(const float*)d_in[6], (const float*)d_in[12]};
  const float* bih[2] = {(const float*)d_in[7], (const float*)d_in[13]};
  const float* bhh[2] = {(const float*)d_in[8], (const float*)d_in[14]};
  const int N = in_sizes[0] / DD;
  const int E = in_sizes[1];

  const size_t nd = (size_t)N * DD;
  char* base = (char*)d_ws;
  float* hA   = (float*)base;                 base += nd * sizeof(float);
  float* hB   = (float*)base;                 base += nd * sizeof(float);
  float* agg  = (float*)base;                 base += nd * sizeof(float);
  float* Wf[2]; float* u[2];
  Wf[0] = (float*)base; base += 3 * DD * DD * sizeof(float);
  Wf[1] = (float*)base; base += 3 * DD * DD * sizeof(float);
  u[0]  = (float*)base; base += 3 * DD * sizeof(float);
  u[1]  = (float*)base; base += 3 * DD * sizeof(float);
  int* deg  = (int*)base; base += (size_t)N * sizeof(int);
  int* ofs  = (int*)base; base += ((size_t)N + 1) * sizeof(int);
  int* cur  = (int*)base; base += (size_t)N * sizeof(int);
  int* eidx = (int*)base; base += (size_t)E * sizeof(int);

  // ---- CSR build (graph is shared by both layers) ----
  hipMemsetAsync(deg, 0, (size_t)N * sizeof(int), stream);
  deg_count<<<(E + 255) / 256, 256, 0, stream>>>(dst, deg, E);
  scan_deg<<<1, 1024, 0, stream>>>(deg, ofs, cur, N);
  fill_csr<<<(E + 255) / 256, 256, 0, stream>>>(src, dst, cur, eidx, E);

  // ---- fused weights per layer ----
  for (int layer = 0; layer < 2; ++layer) {
    fuse_w<<<3 * DD, 128, 0, stream>>>(Wih[layer], W[layer], Wf[layer]);
    fuse_u<<<3, 128, 0, stream>>>(Wih[layer], bb[layer], u[layer]);
  }

  hipMemcpyAsync(hA, in_feat, nd * sizeof(float), hipMemcpyDeviceToDevice, stream);

  float* hcur = hA;
  float* hnxt = hB;
  const int mblocks = (N + 63) / 64;
  const int gblocks = (N + 3) / 4;

  for (int layer = 0; layer < 2; ++layer) {
    for (int step_i = 0; step_i < 8; ++step_i) {
      gather_h<<<gblocks, 256, 0, stream>>>(hcur, ofs, eidx, agg, N);
      int do_relu = (layer == 0 && step_i == 7) ? 1 : 0;
      gru_fused<<<dim3(mblocks, 4), 256, 0, stream>>>(
          agg, hcur, Wf[layer], Whh[layer], bih[layer], bhh[layer],
          u[layer], deg, hnxt, N, do_relu);
      float* t = hcur; hcur = hnxt; hnxt = t;
    }
  }

  hipMemsetAsync(d_out, 0, DD * sizeof(float), stream);
  col_mean<<<256, 256, 0, stream>>>(hcur, (float*)d_out, N);
}

// Round 4
// 3616.368 us; speedup vs baseline: 8.2492x; 2.3759x over previous
//
#include <hip/hip_runtime.h>
#include <hip/hip_bf16.h>
#include <cmath>

#define DD 128

typedef __attribute__((ext_vector_type(8))) short short8v;
typedef __attribute__((ext_vector_type(4))) float floatx4;

__device__ __forceinline__ float sigmoid_f(float x) { return 1.0f / (1.0f + __expf(-x)); }
__device__ __forceinline__ float tanh_f(float x) {
  float e = __expf(2.0f * x);
  return 1.0f - 2.0f / (e + 1.0f);
}
__device__ __forceinline__ unsigned short f2bf(float x) {
  __hip_bfloat16 b = __float2bfloat16(x);
  return *reinterpret_cast<unsigned short*>(&b);
}
__device__ __forceinline__ float bf2f(unsigned short s) {
  return __uint_as_float(((unsigned int)s) << 16);
}

// ---------------- CSR build ----------------
__global__ __launch_bounds__(256) void deg_count(const int* __restrict__ dst,
                                                 int* __restrict__ deg, int E) {
  int e = blockIdx.x * blockDim.x + threadIdx.x;
  if (e < E) atomicAdd(&deg[dst[e]], 1);
}

__global__ __launch_bounds__(1024) void scan_deg(const int* __restrict__ deg,
                                                 int* __restrict__ ofs,
                                                 int* __restrict__ cur, int N) {
  __shared__ int part[1024];
  const int t = threadIdx.x;
  const int chunk = (N + 1023) / 1024;
  const int beg = t * chunk;
  const int end = min(beg + chunk, N);
  int s = 0;
  for (int i = beg; i < end; ++i) s += deg[i];
  part[t] = s;
  __syncthreads();
  if (t == 0) {
    int run = 0;
    for (int i = 0; i < 1024; ++i) { int v = part[i]; part[i] = run; run += v; }
    ofs[N] = run;
  }
  __syncthreads();
  int run = part[t];
  for (int i = beg; i < end; ++i) { ofs[i] = run; cur[i] = run; run += deg[i]; }
}

__global__ __launch_bounds__(256) void fill_csr(const int* __restrict__ src,
                                                const int* __restrict__ dst,
                                                int* __restrict__ cur,
                                                int* __restrict__ eidx, int E) {
  int e = blockIdx.x * blockDim.x + threadIdx.x;
  if (e < E) {
    int p = atomicAdd(&cur[dst[e]], 1);
    eidx[p] = src[e];
  }
}

// ---------------- weight prep ----------------
// Wf = Wih @ W (fp32) -> Wc32 [384][128]
__global__ __launch_bounds__(128) void fuse_w(const float* __restrict__ Wih,
                                              const float* __restrict__ W,
                                              float* __restrict__ Wc32) {
  int r = blockIdx.x;          // 0..383
  int k = threadIdx.x;         // 0..127
  float acc = 0.0f;
  for (int j = 0; j < DD; ++j) acc = fmaf(Wih[r * DD + j], W[j * DD + k], acc);
  Wc32[(size_t)r * DD + k] = acc;
}

__global__ __launch_bounds__(128) void fuse_u(const float* __restrict__ Wih,
                                              const float* __restrict__ b,
                                              float* __restrict__ u) {
  int r = blockIdx.x * 128 + threadIdx.x;
  if (r < 3 * DD) {
    float acc = 0.0f;
    for (int j = 0; j < DD; ++j) acc = fmaf(Wih[r * DD + j], b[j], acc);
    u[r] = acc;
  }
}

// split fp32 weights (rows<384: Wf from Wc32; rows>=384: Whh) into 3 bf16 planes
__global__ __launch_bounds__(256) void split_w(const float* __restrict__ Wf,
                                               const float* __restrict__ Whh,
                                               unsigned short* __restrict__ Wp) {
  int i = blockIdx.x * 256 + threadIdx.x;  // 0 .. 768*128
  const int TOT = 6 * DD * DD;             // 98304
  if (i < TOT) {
    int r = i >> 7;
    float x = (r < 3 * DD) ? Wf[i] : Whh[i - 3 * DD * DD];
    unsigned short hb = f2bf(x);
    float xr = x - bf2f(hb);
    unsigned short mb = f2bf(xr);
    float x2 = xr - bf2f(mb);
    unsigned short lb = f2bf(x2);
    Wp[i] = hb;
    Wp[TOT + i] = mb;
    Wp[2 * TOT + i] = lb;
  }
}

// ---------------- aggregation (fp32): agg[n] = sum_{e in CSR[n]} h[eidx[e]] ----------------
__global__ __launch_bounds__(256) void gather_h(const float* __restrict__ h,
                                                const int* __restrict__ ofs,
                                                const int* __restrict__ eidx,
                                                float* __restrict__ agg, int N) {
  int node = blockIdx.x * 4 + (threadIdx.x >> 6);
  if (node >= N) return;
  int lane = threadIdx.x & 63;
  int beg = ofs[node], end = ofs[node + 1];
  float2 acc0 = {0.0f, 0.0f}, acc1 = {0.0f, 0.0f};
  int e = beg;
  for (; e + 1 < end; e += 2) {
    int s0 = eidx[e], s1 = eidx[e + 1];
    float2 v0 = *(const float2*)(h + (size_t)s0 * DD + lane * 2);
    float2 v1 = *(const float2*)(h + (size_t)s1 * DD + lane * 2);
    acc0.x += v0.x; acc0.y += v0.y;
    acc1.x += v1.x; acc1.y += v1.y;
  }
  if (e < end) {
    int s = eidx[e];
    float2 v = *(const float2*)(h + (size_t)s * DD + lane * 2);
    acc0.x += v.x; acc0.y += v.y;
  }
  float2 r;
  r.x = acc0.x + acc1.x;
  r.y = acc0.y + acc1.y;
  *(float2*)(agg + (size_t)node * DD + lane * 2) = r;
}

// load 8 fp32 at p[0..8), split into NP bf16 planes (hi, mid, lo)
template <int NP>
__device__ __forceinline__ void load_split(const float* p, short8v& q0, short8v& q1, short8v& q2) {
  float4 v0 = *(const float4*)(p);
  float4 v1 = *(const float4*)(p + 4);
  float f0 = v0.x, f1 = v0.y, f2 = v0.z, f3 = v0.w;
  float f4 = v1.x, f5 = v1.y, f6 = v1.z, f7 = v1.w;
#define SPLIT1(e, x)                                        \
  {                                                         \
    unsigned short hb = f2bf(x);                            \
    q0[e] = (short)hb;                                      \
    if (NP > 1) {                                           \
      float xr = (x) - bf2f(hb);                            \
      unsigned short mb = f2bf(xr);                         \
      q1[e] = (short)mb;                                    \
      if (NP > 2) {                                         \
        float x2 = xr - bf2f(mb);                           \
        q2[e] = (short)f2bf(x2);                            \
      }                                                     \
    }                                                       \
  }
  SPLIT1(0, f0) SPLIT1(1, f1) SPLIT1(2, f2) SPLIT1(3, f3)
  SPLIT1(4, f4) SPLIT1(5, f5) SPLIT1(6, f6) SPLIT1(7, f7)
#undef SPLIT1
}

// ---------------- fused GRU, fp32-accurate via 3-plane bf16 MFMA ----------------
// Block: 128 rows x 32 gate-cols; 4 waves of 32 rows each.
// acc[g][ct][rt] = sum over (A-plane pa, W-plane wp) in {hh,hm,mh,hl,lh,mm}.
__global__ __launch_bounds__(256) void gru_mfma3(
    const float* __restrict__ Agg, const float* __restrict__ H,
    const unsigned short* __restrict__ Wp,   // [3][768][128] bf16 bits
    const float* __restrict__ bih, const float* __restrict__ bhh,
    const float* __restrict__ u, const int* __restrict__ deg,
    float* __restrict__ Hout, int N, int do_relu)
{
  __shared__ short sW[192 * 136];  // one weight plane: 6 gates x 32 cols, k padded
  const int tid = threadIdx.x;
  const int wid = tid >> 6;
  const int lane = tid & 63;
  const int rowBase = blockIdx.x * 128 + wid * 32;
  const int j0 = blockIdx.y * 32;
  const int lrow = lane & 15;
  const int lk = (lane >> 4) * 8;

  floatx4 acc[6][2][2];
#pragma unroll
  for (int g = 0; g < 6; ++g)
#pragma unroll
    for (int ct = 0; ct < 2; ++ct)
#pragma unroll
      for (int rt = 0; rt < 2; ++rt) acc[g][ct][rt] = (floatx4){0.f, 0.f, 0.f, 0.f};

  int r0 = rowBase + lrow;       if (r0 >= N) r0 = N - 1;
  int r1 = rowBase + 16 + lrow;  if (r1 >= N) r1 = N - 1;
  const float* a0p = Agg + (size_t)r0 * DD;
  const float* a1p = Agg + (size_t)r1 * DD;
  const float* h0p = H + (size_t)r0 * DD;
  const float* h1p = H + (size_t)r1 * DD;

#pragma unroll
  for (int wp = 0; wp < 3; ++wp) {
    const int NPA = 3 - wp;  // A-planes paired with this W-plane
    __syncthreads();
    // stage weight plane wp: 192 rows x 128 k bf16
    for (int ch = tid; ch < 3072; ch += 256) {
      int w = ch >> 4;
      int kb = (ch & 15) << 3;
      int g = w >> 5, cc = w & 31;
      short8v v = *(const short8v*)(Wp + (size_t)wp * (6 * DD * DD) +
                                    (size_t)(g * DD + j0 + cc) * DD + kb);
      *(short8v*)(&sW[w * 136 + kb]) = v;
    }
    __syncthreads();

#pragma unroll
    for (int k0 = 0; k0 < DD; k0 += 32) {
      short8v fA0[3], fA1[3], fH0[3], fH1[3];
      if (NPA == 3) {
        load_split<3>(a0p + k0 + lk, fA0[0], fA0[1], fA0[2]);
        load_split<3>(a1p + k0 + lk, fA1[0], fA1[1], fA1[2]);
        load_split<3>(h0p + k0 + lk, fH0[0], fH0[1], fH0[2]);
        load_split<3>(h1p + k0 + lk, fH1[0], fH1[1], fH1[2]);
      } else if (NPA == 2) {
        load_split<2>(a0p + k0 + lk, fA0[0], fA0[1], fA0[2]);
        load_split<2>(a1p + k0 + lk, fA1[0], fA1[1], fA1[2]);
        load_split<2>(h0p + k0 + lk, fH0[0], fH0[1], fH0[2]);
        load_split<2>(h1p + k0 + lk, fH1[0], fH1[1], fH1[2]);
      } else {
        load_split<1>(a0p + k0 + lk, fA0[0], fA0[1], fA0[2]);
        load_split<1>(a1p + k0 + lk, fA1[0], fA1[1], fA1[2]);
        load_split<1>(h0p + k0 + lk, fH0[0], fH0[1], fH0[2]);
        load_split<1>(h1p + k0 + lk, fH1[0], fH1[1], fH1[2]);
      }
#pragma unroll
      for (int g = 0; g < 6; ++g) {
#pragma unroll
        for (int ct = 0; ct < 2; ++ct) {
          short8v bf = *(const short8v*)(&sW[(g * 32 + ct * 16 + lrow) * 136 + k0 + lk]);
#pragma unroll
          for (int pa = 0; pa < 3; ++pa) {
            if (pa < NPA) {
              short8v x0 = (g < 3) ? fA0[pa] : fH0[pa];
              short8v x1 = (g < 3) ? fA1[pa] : fH1[pa];
              acc[g][ct][0] = __builtin_amdgcn_mfma_f32_16x16x32_bf16(x0, bf, acc[g][ct][0], 0, 0, 0);
              acc[g][ct][1] = __builtin_amdgcn_mfma_f32_16x16x32_bf16(x1, bf, acc[g][ct][1], 0, 0, 0);
            }
          }
        }
      }
    }
  }

  // epilogue. C/D layout: col = lane&15, row = (lane>>4)*4 + reg
  float bi_r[2], bi_z[2], bi_n[2], bh_r[2], bh_z[2], bh_n[2], u_r[2], u_z[2], u_n[2];
#pragma unroll
  for (int ct = 0; ct < 2; ++ct) {
    int c = j0 + ct * 16 + lrow;
    bi_r[ct] = bih[c];  bi_z[ct] = bih[DD + c];  bi_n[ct] = bih[2 * DD + c];
    bh_r[ct] = bhh[c];  bh_z[ct] = bhh[DD + c];  bh_n[ct] = bhh[2 * DD + c];
    u_r[ct]  = u[c];    u_z[ct]  = u[DD + c];    u_n[ct]  = u[2 * DD + c];
  }

#pragma unroll
  for (int rt = 0; rt < 2; ++rt) {
#pragma unroll
    for (int q = 0; q < 4; ++q) {
      int row = rowBase + rt * 16 + (lane >> 4) * 4 + q;
      if (row < N) {
        float dg = (float)deg[row];
#pragma unroll
        for (int ct = 0; ct < 2; ++ct) {
          int c = j0 + ct * 16 + lrow;
          float ir = acc[0][ct][rt][q] + bi_r[ct] + dg * u_r[ct];
          float iz = acc[1][ct][rt][q] + bi_z[ct] + dg * u_z[ct];
          float in = acc[2][ct][rt][q] + bi_n[ct] + dg * u_n[ct];
          float hr = acc[3][ct][rt][q] + bh_r[ct];
          float hz = acc[4][ct][rt][q] + bh_z[ct];
          float hn = acc[5][ct][rt][q] + bh_n[ct];
          float rg = sigmoid_f(ir + hr);
          float zg = sigmoid_f(iz + hz);
          float ng = tanh_f(in + rg * hn);
          float hold = H[(size_t)row * DD + c];
          float out = (1.0f - zg) * ng + zg * hold;
          if (do_relu) out = fmaxf(out, 0.0f);
          Hout[(size_t)row * DD + c] = out;
        }
      }
    }
  }
}

// out[c] = mean over rows of H[:, c]; out must be zeroed first
__global__ __launch_bounds__(256) void col_mean(
    const float* __restrict__ H, float* __restrict__ out, int N)
{
  __shared__ float s[256];
  int c = threadIdx.x & 127;
  int rg = threadIdx.x >> 7;
  float acc = 0.0f;
  for (int r = blockIdx.x * 2 + rg; r < N; r += gridDim.x * 2)
    acc += H[(size_t)r * DD + c];
  s[threadIdx.x] = acc;
  __syncthreads();
  if (threadIdx.x < 128) {
    float v = (s[threadIdx.x] + s[threadIdx.x + 128]) * (1.0f / (float)N);
    unsafeAtomicAdd(out + c, v);
  }
}

extern "C" void kernel_launch(void* const* d_in, const int* in_sizes, int n_in,
                              void* d_out, int out_size, void* d_ws, size_t ws_size,
                              hipStream_t stream) {
  const float* in_feat = (const float*)d_in[0];
  const int* src = (const int*)d_in[1];
  const int* dst = (const int*)d_in[2];
  const float* W[2]   = {(const float*)d_in[3], (const float*)d_in[9]};
  const float* bb[2]  = {(const float*)d_in[4], (const float*)d_in[10]};
  const float* Wih[2] = {(const float*)d_in[5], (const float*)d_in[11]};
  const float* Whh[2] = {(const float*)d_in[6], (const float*)d_in[12]};
  const float* bih[2] = {(const float*)d_in[7], (const float*)d_in[13]};
  const float* bhh[2] = {(const float*)d_in[8], (const float*)d_in[14]};
  const int N = in_sizes[0] / DD;
  const int E = in_sizes[1];

  const size_t nd = (size_t)N * DD;
  char* base = (char*)d_ws;
  float* hA  = (float*)base; base += nd * sizeof(float);
  float* hB  = (float*)base; base += nd * sizeof(float);
  float* agg = (float*)base; base += nd * sizeof(float);
  float* Wc32 = (float*)base; base += (size_t)3 * DD * DD * sizeof(float);
  unsigned short* Wp[2];
  Wp[0] = (unsigned short*)base; base += (size_t)3 * 6 * DD * DD * sizeof(unsigned short);
  Wp[1] = (unsigned short*)base; base += (size_t)3 * 6 * DD * DD * sizeof(unsigned short);
  float* u[2];
  u[0] = (float*)base; base += 3 * DD * sizeof(float);
  u[1] = (float*)base; base += 3 * DD * sizeof(float);
  int* deg  = (int*)base; base += (size_t)N * sizeof(int);
  int* ofs  = (int*)base; base += ((size_t)N + 1) * sizeof(int);
  int* cur  = (int*)base; base += (size_t)N * sizeof(int);
  int* eidx = (int*)base; base += (size_t)E * sizeof(int);

  // ---- CSR build ----
  hipMemsetAsync(deg, 0, (size_t)N * sizeof(int), stream);
  deg_count<<<(E + 255) / 256, 256, 0, stream>>>(dst, deg, E);
  scan_deg<<<1, 1024, 0, stream>>>(deg, ofs, cur, N);
  fill_csr<<<(E + 255) / 256, 256, 0, stream>>>(src, dst, cur, eidx, E);

  // ---- weights: fuse in fp32, split into 3 bf16 planes ----
  for (int layer = 0; layer < 2; ++layer) {
    fuse_w<<<3 * DD, 128, 0, stream>>>(Wih[layer], W[layer], Wc32);
    split_w<<<(6 * DD * DD + 255) / 256, 256, 0, stream>>>(Wc32, Whh[layer], Wp[layer]);
    fuse_u<<<3, 128, 0, stream>>>(Wih[layer], bb[layer], u[layer]);
  }

  hipMemcpyAsync(hA, in_feat, nd * sizeof(float), hipMemcpyDeviceToDevice, stream);

  float* hcur = hA;
  float* hnxt = hB;
  const int gblocks = (N + 3) / 4;
  const int mblocks = (N + 127) / 128;

  for (int layer = 0; layer < 2; ++layer) {
    for (int step_i = 0; step_i < 8; ++step_i) {
      gather_h<<<gblocks, 256, 0, stream>>>(hcur, ofs, eidx, agg, N);
      int do_relu = (layer == 0 && step_i == 7) ? 1 : 0;
      gru_mfma3<<<dim3(mblocks, 4), 256, 0, stream>>>(
          agg, hcur, Wp[layer], bih[layer], bhh[layer],
          u[layer], deg, hnxt, N, do_relu);
      float* t = hcur; hcur = hnxt; hnxt = t;
    }
  }

  hipMemsetAsync(d_out, 0, DD * sizeof(float), stream);
  col_mean<<<256, 256, 0, stream>>>(hcur, (float*)d_out, N);
}

// Round 5
// 3264.815 us; speedup vs baseline: 9.1374x; 1.1077x over previous
//
#include <hip/hip_runtime.h>
#include <hip/hip_bf16.h>
#include <cmath>

#define DD 128

typedef __attribute__((ext_vector_type(8))) short short8v;
typedef __attribute__((ext_vector_type(4))) float floatx4;

__device__ __forceinline__ float sigmoid_f(float x) { return 1.0f / (1.0f + __expf(-x)); }
__device__ __forceinline__ float tanh_f(float x) {
  float e = __expf(2.0f * x);
  return 1.0f - 2.0f / (e + 1.0f);
}
__device__ __forceinline__ unsigned short f2bf(float x) {
  __hip_bfloat16 b = __float2bfloat16(x);
  return *reinterpret_cast<unsigned short*>(&b);
}
__device__ __forceinline__ float bf2f(unsigned short s) {
  return __uint_as_float(((unsigned int)s) << 16);
}

// ---------------- CSR build ----------------
__global__ __launch_bounds__(256) void deg_count(const int* __restrict__ dst,
                                                 int* __restrict__ deg, int E) {
  int e = blockIdx.x * blockDim.x + threadIdx.x;
  if (e < E) atomicAdd(&deg[dst[e]], 1);
}

__global__ __launch_bounds__(1024) void scan_deg(const int* __restrict__ deg,
                                                 int* __restrict__ ofs,
                                                 int* __restrict__ cur, int N) {
  __shared__ int part[1024];
  const int t = threadIdx.x;
  const int chunk = (N + 1023) / 1024;
  const int beg = t * chunk;
  const int end = min(beg + chunk, N);
  int s = 0;
  for (int i = beg; i < end; ++i) s += deg[i];
  part[t] = s;
  __syncthreads();
  if (t == 0) {
    int run = 0;
    for (int i = 0; i < 1024; ++i) { int v = part[i]; part[i] = run; run += v; }
    ofs[N] = run;
  }
  __syncthreads();
  int run = part[t];
  for (int i = beg; i < end; ++i) { ofs[i] = run; cur[i] = run; run += deg[i]; }
}

__global__ __launch_bounds__(256) void fill_csr(const int* __restrict__ src,
                                                const int* __restrict__ dst,
                                                int* __restrict__ cur,
                                                int* __restrict__ eidx, int E) {
  int e = blockIdx.x * blockDim.x + threadIdx.x;
  if (e < E) {
    int p = atomicAdd(&cur[dst[e]], 1);
    eidx[p] = src[e];
  }
}

// ---------------- weight prep ----------------
__global__ __launch_bounds__(128) void fuse_w(const float* __restrict__ Wih,
                                              const float* __restrict__ W,
                                              float* __restrict__ Wc32) {
  int r = blockIdx.x;          // 0..383
  int k = threadIdx.x;         // 0..127
  float acc = 0.0f;
  for (int j = 0; j < DD; ++j) acc = fmaf(Wih[r * DD + j], W[j * DD + k], acc);
  Wc32[(size_t)r * DD + k] = acc;
}

__global__ __launch_bounds__(128) void fuse_u(const float* __restrict__ Wih,
                                              const float* __restrict__ b,
                                              float* __restrict__ u) {
  int r = blockIdx.x * 128 + threadIdx.x;
  if (r < 3 * DD) {
    float acc = 0.0f;
    for (int j = 0; j < DD; ++j) acc = fmaf(Wih[r * DD + j], b[j], acc);
    u[r] = acc;
  }
}

// split fp32 weights (rows<384: Wf; rows>=384: Whh) into 3 bf16 planes
__global__ __launch_bounds__(256) void split_w(const float* __restrict__ Wf,
                                               const float* __restrict__ Whh,
                                               unsigned short* __restrict__ Wp) {
  int i = blockIdx.x * 256 + threadIdx.x;
  const int TOT = 6 * DD * DD;             // 98304
  if (i < TOT) {
    int r = i >> 7;
    float x = (r < 3 * DD) ? Wf[i] : Whh[i - 3 * DD * DD];
    unsigned short hb = f2bf(x);
    float xr = x - bf2f(hb);
    unsigned short mb = f2bf(xr);
    float x2 = xr - bf2f(mb);
    unsigned short lb = f2bf(x2);
    Wp[i] = hb;
    Wp[TOT + i] = mb;
    Wp[2 * TOT + i] = lb;
  }
}

// ---------------- aggregation (fp32): agg[n] = sum_{e in CSR[n]} h[eidx[e]] ----------------
__global__ __launch_bounds__(256) void gather_h(const float* __restrict__ h,
                                                const int* __restrict__ ofs,
                                                const int* __restrict__ eidx,
                                                float* __restrict__ agg, int N) {
  int node = blockIdx.x * 8 + (threadIdx.x >> 5);
  if (node >= N) return;
  int l = (threadIdx.x & 31) << 2;
  int beg = ofs[node], end = ofs[node + 1];
  float4 a0 = {0.f, 0.f, 0.f, 0.f}, a1 = {0.f, 0.f, 0.f, 0.f};
  int e = beg;
  for (; e + 1 < end; e += 2) {
    int s0 = eidx[e], s1 = eidx[e + 1];
    float4 v0 = *(const float4*)(h + (size_t)s0 * DD + l);
    float4 v1 = *(const float4*)(h + (size_t)s1 * DD + l);
    a0.x += v0.x; a0.y += v0.y; a0.z += v0.z; a0.w += v0.w;
    a1.x += v1.x; a1.y += v1.y; a1.z += v1.z; a1.w += v1.w;
  }
  if (e < end) {
    float4 v = *(const float4*)(h + (size_t)eidx[e] * DD + l);
    a0.x += v.x; a0.y += v.y; a0.z += v.z; a0.w += v.w;
  }
  float4 r;
  r.x = a0.x + a1.x; r.y = a0.y + a1.y; r.z = a0.z + a1.z; r.w = a0.w + a1.w;
  *(float4*)(agg + (size_t)node * DD + l) = r;
}

// split 8 fp32 at p into 3 bf16 planes
__device__ __forceinline__ void split8(const float* p, short8v& q0, short8v& q1, short8v& q2) {
  float4 v0 = *(const float4*)(p);
  float4 v1 = *(const float4*)(p + 4);
  float f[8] = {v0.x, v0.y, v0.z, v0.w, v1.x, v1.y, v1.z, v1.w};
#pragma unroll
  for (int e = 0; e < 8; ++e) {
    float x = f[e];
    unsigned short hb = f2bf(x);
    float xr = x - bf2f(hb);
    unsigned short mb = f2bf(xr);
    float x2 = xr - bf2f(mb);
    q0[e] = (short)hb;
    q1[e] = (short)mb;
    q2[e] = (short)f2bf(x2);
  }
}

// ---------------- fused GRU, fp32-accurate via 3-plane bf16 MFMA ----------------
// Block: 64 rows x 64 gate-cols; 4 waves of 16 rows each.
// arr=0: gates r/z/n from Agg@Wf^T (planes); arr=1: from H@Whh^T.
// Per arr: load+split A once (3 planes in regs), 3 wp passes over LDS-staged W planes.
__global__ __launch_bounds__(256) void gru_mfma3(
    const float* __restrict__ Agg, const float* __restrict__ H,
    const unsigned short* __restrict__ Wp,   // [3][768][128] bf16 bits
    const float* __restrict__ bih, const float* __restrict__ bhh,
    const float* __restrict__ u, const int* __restrict__ deg,
    float* __restrict__ Hout, int N, int do_relu)
{
  __shared__ short sW[192 * 136];  // one plane, 3 gates x 64 cols, k padded to 136
  const int TOT = 6 * DD * DD;
  const int tid = threadIdx.x;
  const int wid = tid >> 6;
  const int lane = tid & 63;
  const int lrow = lane & 15;
  const int lk = (lane >> 4) * 8;
  const int rowBase = blockIdx.x * 64 + wid * 16;
  const int j0 = blockIdx.y * 64;

  floatx4 acc[6][4];
#pragma unroll
  for (int g = 0; g < 6; ++g)
#pragma unroll
    for (int ct = 0; ct < 4; ++ct) acc[g][ct] = (floatx4){0.f, 0.f, 0.f, 0.f};

  int r0 = rowBase + lrow;
  if (r0 >= N) r0 = N - 1;

#pragma unroll
  for (int arr = 0; arr < 2; ++arr) {
    const float* ap = (arr ? H : Agg) + (size_t)r0 * DD;
    // load + split A once: frag[plane][k-chunk]
    short8v frag[3][4];
#pragma unroll
    for (int kc = 0; kc < 4; ++kc)
      split8(ap + kc * 32 + lk, frag[0][kc], frag[1][kc], frag[2][kc]);

#pragma unroll
    for (int wp = 0; wp < 3; ++wp) {
      __syncthreads();
      // stage plane wp of this arr's 3 gates x 64 cols
      for (int ch = tid; ch < 3072; ch += 256) {
        int w = ch >> 4;               // 0..191 = g_local*64 + cc
        int kb = (ch & 15) << 3;
        int gl = w >> 6, cc = w & 63;
        int grow = arr * 384 + gl * DD + j0 + cc;
        short8v v = *(const short8v*)(Wp + (size_t)wp * TOT + (size_t)grow * DD + kb);
        *(short8v*)(&sW[w * 136 + kb]) = v;
      }
      __syncthreads();
      const int NPA = 3 - wp;
#pragma unroll
      for (int kc = 0; kc < 4; ++kc) {
#pragma unroll
        for (int gl = 0; gl < 3; ++gl) {
#pragma unroll
          for (int ct = 0; ct < 4; ++ct) {
            short8v bf = *(const short8v*)(&sW[(gl * 64 + ct * 16 + lrow) * 136 + kc * 32 + lk]);
#pragma unroll
            for (int pa = 0; pa < 3; ++pa) {
              if (pa < NPA) {
                acc[arr * 3 + gl][ct] =
                    __builtin_amdgcn_mfma_f32_16x16x32_bf16(frag[pa][kc], bf,
                                                            acc[arr * 3 + gl][ct], 0, 0, 0);
              }
            }
          }
        }
      }
    }
  }

  // epilogue. C/D layout: col = lane&15, row = (lane>>4)*4 + reg
  float bi_r[4], bi_z[4], bi_n[4], bh_r[4], bh_z[4], bh_n[4], u_r[4], u_z[4], u_n[4];
#pragma unroll
  for (int ct = 0; ct < 4; ++ct) {
    int c = j0 + ct * 16 + lrow;
    bi_r[ct] = bih[c];  bi_z[ct] = bih[DD + c];  bi_n[ct] = bih[2 * DD + c];
    bh_r[ct] = bhh[c];  bh_z[ct] = bhh[DD + c];  bh_n[ct] = bhh[2 * DD + c];
    u_r[ct]  = u[c];    u_z[ct]  = u[DD + c];    u_n[ct]  = u[2 * DD + c];
  }

#pragma unroll
  for (int q = 0; q < 4; ++q) {
    int row = rowBase + (lane >> 4) * 4 + q;
    if (row < N) {
      float dg = (float)deg[row];
#pragma unroll
      for (int ct = 0; ct < 4; ++ct) {
        int c = j0 + ct * 16 + lrow;
        float ir = acc[0][ct][q] + bi_r[ct] + dg * u_r[ct];
        float iz = acc[1][ct][q] + bi_z[ct] + dg * u_z[ct];
        float in = acc[2][ct][q] + bi_n[ct] + dg * u_n[ct];
        float hr = acc[3][ct][q] + bh_r[ct];
        float hz = acc[4][ct][q] + bh_z[ct];
        float hn = acc[5][ct][q] + bh_n[ct];
        float rg = sigmoid_f(ir + hr);
        float zg = sigmoid_f(iz + hz);
        float ng = tanh_f(in + rg * hn);
        float hold = H[(size_t)row * DD + c];
        float out = (1.0f - zg) * ng + zg * hold;
        if (do_relu) out = fmaxf(out, 0.0f);
        Hout[(size_t)row * DD + c] = out;
      }
    }
  }
}

// out[c] = mean over rows of H[:, c]; out must be zeroed first
__global__ __launch_bounds__(256) void col_mean(
    const float* __restrict__ H, float* __restrict__ out, int N)
{
  __shared__ float s[256];
  int c = threadIdx.x & 127;
  int rg = threadIdx.x >> 7;
  float acc = 0.0f;
  for (int r = blockIdx.x * 2 + rg; r < N; r += gridDim.x * 2)
    acc += H[(size_t)r * DD + c];
  s[threadIdx.x] = acc;
  __syncthreads();
  if (threadIdx.x < 128) {
    float v = (s[threadIdx.x] + s[threadIdx.x + 128]) * (1.0f / (float)N);
    unsafeAtomicAdd(out + c, v);
  }
}

extern "C" void kernel_launch(void* const* d_in, const int* in_sizes, int n_in,
                              void* d_out, int out_size, void* d_ws, size_t ws_size,
                              hipStream_t stream) {
  const float* in_feat = (const float*)d_in[0];
  const int* src = (const int*)d_in[1];
  const int* dst = (const int*)d_in[2];
  const float* W[2]   = {(const float*)d_in[3], (const float*)d_in[9]};
  const float* bb[2]  = {(const float*)d_in[4], (const float*)d_in[10]};
  const float* Wih[2] = {(const float*)d_in[5], (const float*)d_in[11]};
  const float* Whh[2] = {(const float*)d_in[6], (const float*)d_in[12]};
  const float* bih[2] = {(const float*)d_in[7], (const float*)d_in[13]};
  const float* bhh[2] = {(const float*)d_in[8], (const float*)d_in[14]};
  const int N = in_sizes[0] / DD;
  const int E = in_sizes[1];

  const size_t nd = (size_t)N * DD;
  char* base = (char*)d_ws;
  float* hA  = (float*)base; base += nd * sizeof(float);
  float* hB  = (float*)base; base += nd * sizeof(float);
  float* agg = (float*)base; base += nd * sizeof(float);
  float* Wc32 = (float*)base; base += (size_t)3 * DD * DD * sizeof(float);
  unsigned short* Wp[2];
  Wp[0] = (unsigned short*)base; base += (size_t)3 * 6 * DD * DD * sizeof(unsigned short);
  Wp[1] = (unsigned short*)base; base += (size_t)3 * 6 * DD * DD * sizeof(unsigned short);
  float* u[2];
  u[0] = (float*)base; base += 3 * DD * sizeof(float);
  u[1] = (float*)base; base += 3 * DD * sizeof(float);
  int* deg  = (int*)base; base += (size_t)N * sizeof(int);
  int* ofs  = (int*)base; base += ((size_t)N + 1) * sizeof(int);
  int* cur  = (int*)base; base += (size_t)N * sizeof(int);
  int* eidx = (int*)base; base += (size_t)E * sizeof(int);

  // ---- CSR build ----
  hipMemsetAsync(deg, 0, (size_t)N * sizeof(int), stream);
  deg_count<<<(E + 255) / 256, 256, 0, stream>>>(dst, deg, E);
  scan_deg<<<1, 1024, 0, stream>>>(deg, ofs, cur, N);
  fill_csr<<<(E + 255) / 256, 256, 0, stream>>>(src, dst, cur, eidx, E);

  // ---- weights: fuse in fp32, split into 3 bf16 planes ----
  for (int layer = 0; layer < 2; ++layer) {
    fuse_w<<<3 * DD, 128, 0, stream>>>(Wih[layer], W[layer], Wc32);
    split_w<<<(6 * DD * DD + 255) / 256, 256, 0, stream>>>(Wc32, Whh[layer], Wp[layer]);
    fuse_u<<<3, 128, 0, stream>>>(Wih[layer], bb[layer], u[layer]);
  }

  hipMemcpyAsync(hA, in_feat, nd * sizeof(float), hipMemcpyDeviceToDevice, stream);

  float* hcur = hA;
  float* hnxt = hB;
  const int gblocks = (N + 7) / 8;
  const int mblocks = (N + 63) / 64;

  for (int layer = 0; layer < 2; ++layer) {
    for (int step_i = 0; step_i < 8; ++step_i) {
      gather_h<<<gblocks, 256, 0, stream>>>(hcur, ofs, eidx, agg, N);
      int do_relu = (layer == 0 && step_i == 7) ? 1 : 0;
      gru_mfma3<<<dim3(mblocks, 2), 256, 0, stream>>>(
          agg, hcur, Wp[layer], bih[layer], bhh[layer],
          u[layer], deg, hnxt, N, do_relu);
      float* t = hcur; hcur = hnxt; hnxt = t;
    }
  }

  hipMemsetAsync(d_out, 0, DD * sizeof(float), stream);
  col_mean<<<256, 256, 0, stream>>>(hcur, (float*)d_out, N);
}

// Round 6
// 2331.507 us; speedup vs baseline: 12.7952x; 1.4003x over previous
//
#include <hip/hip_runtime.h>
#include <hip/hip_bf16.h>
#include <cmath>

#define DD 128

typedef __attribute__((ext_vector_type(8))) short short8v;
typedef __attribute__((ext_vector_type(4))) float floatx4;

__device__ __forceinline__ float sigmoid_f(float x) { return 1.0f / (1.0f + __expf(-x)); }
__device__ __forceinline__ float tanh_f(float x) {
  float e = __expf(2.0f * x);
  return 1.0f - 2.0f / (e + 1.0f);
}
__device__ __forceinline__ unsigned short f2bf(float x) {
  __hip_bfloat16 b = __float2bfloat16(x);
  return *reinterpret_cast<unsigned short*>(&b);
}
__device__ __forceinline__ float bf2f(unsigned short s) {
  return __uint_as_float(((unsigned int)s) << 16);
}

// ---------------- CSR build ----------------
__global__ __launch_bounds__(256) void deg_count(const int* __restrict__ dst,
                                                 int* __restrict__ deg, int E) {
  int e = blockIdx.x * blockDim.x + threadIdx.x;
  if (e < E) atomicAdd(&deg[dst[e]], 1);
}

__global__ __launch_bounds__(1024) void scan_deg(const int* __restrict__ deg,
                                                 int* __restrict__ ofs,
                                                 int* __restrict__ cur, int N) {
  __shared__ int part[1024];
  const int t = threadIdx.x;
  const int chunk = (N + 1023) / 1024;
  const int beg = t * chunk;
  const int end = min(beg + chunk, N);
  int s = 0;
  for (int i = beg; i < end; ++i) s += deg[i];
  part[t] = s;
  __syncthreads();
  if (t == 0) {
    int run = 0;
    for (int i = 0; i < 1024; ++i) { int v = part[i]; part[i] = run; run += v; }
    ofs[N] = run;
  }
  __syncthreads();
  int run = part[t];
  for (int i = beg; i < end; ++i) { ofs[i] = run; cur[i] = run; run += deg[i]; }
}

__global__ __launch_bounds__(256) void fill_csr(const int* __restrict__ src,
                                                const int* __restrict__ dst,
                                                int* __restrict__ cur,
                                                int* __restrict__ eidx, int E) {
  int e = blockIdx.x * blockDim.x + threadIdx.x;
  if (e < E) {
    int p = atomicAdd(&cur[dst[e]], 1);
    eidx[p] = src[e];
  }
}

// ---------------- weight prep ----------------
__global__ __launch_bounds__(128) void fuse_w(const float* __restrict__ Wih,
                                              const float* __restrict__ W,
                                              float* __restrict__ Wc32) {
  int r = blockIdx.x;          // 0..383
  int k = threadIdx.x;         // 0..127
  float acc = 0.0f;
  for (int j = 0; j < DD; ++j) acc = fmaf(Wih[r * DD + j], W[j * DD + k], acc);
  Wc32[(size_t)r * DD + k] = acc;
}

__global__ __launch_bounds__(128) void fuse_u(const float* __restrict__ Wih,
                                              const float* __restrict__ b,
                                              float* __restrict__ u) {
  int r = blockIdx.x * 128 + threadIdx.x;
  if (r < 3 * DD) {
    float acc = 0.0f;
    for (int j = 0; j < DD; ++j) acc = fmaf(Wih[r * DD + j], b[j], acc);
    u[r] = acc;
  }
}

// split fp32 weights (rows<384: Wf; rows>=384: Whh) into 3 bf16 planes
__global__ __launch_bounds__(256) void split_w(const float* __restrict__ Wf,
                                               const float* __restrict__ Whh,
                                               unsigned short* __restrict__ Wp) {
  int i = blockIdx.x * 256 + threadIdx.x;
  const int TOT = 6 * DD * DD;             // 98304
  if (i < TOT) {
    int r = i >> 7;
    float x = (r < 3 * DD) ? Wf[i] : Whh[i - 3 * DD * DD];
    unsigned short hb = f2bf(x);
    float xr = x - bf2f(hb);
    unsigned short mb = f2bf(xr);
    float x2 = xr - bf2f(mb);
    unsigned short lb = f2bf(x2);
    Wp[i] = hb;
    Wp[TOT + i] = mb;
    Wp[2 * TOT + i] = lb;
  }
}

// ---------------- aggregation (fp32): agg[n] = sum_{e in CSR[n]} h[eidx[e]] ----------------
__global__ __launch_bounds__(256) void gather_h(const float* __restrict__ h,
                                                const int* __restrict__ ofs,
                                                const int* __restrict__ eidx,
                                                float* __restrict__ agg, int N) {
  int node = blockIdx.x * 8 + (threadIdx.x >> 5);
  if (node >= N) return;
  int l = (threadIdx.x & 31) << 2;
  int beg = ofs[node], end = ofs[node + 1];
  float4 a0 = {0.f, 0.f, 0.f, 0.f}, a1 = {0.f, 0.f, 0.f, 0.f};
  int e = beg;
  for (; e + 1 < end; e += 2) {
    int s0 = eidx[e], s1 = eidx[e + 1];
    float4 v0 = *(const float4*)(h + (size_t)s0 * DD + l);
    float4 v1 = *(const float4*)(h + (size_t)s1 * DD + l);
    a0.x += v0.x; a0.y += v0.y; a0.z += v0.z; a0.w += v0.w;
    a1.x += v1.x; a1.y += v1.y; a1.z += v1.z; a1.w += v1.w;
  }
  if (e < end) {
    float4 v = *(const float4*)(h + (size_t)eidx[e] * DD + l);
    a0.x += v.x; a0.y += v.y; a0.z += v.z; a0.w += v.w;
  }
  float4 r;
  r.x = a0.x + a1.x; r.y = a0.y + a1.y; r.z = a0.z + a1.z; r.w = a0.w + a1.w;
  *(float4*)(agg + (size_t)node * DD + l) = r;
}

// split 8 fp32 at p into 3 bf16 planes
__device__ __forceinline__ void split8(const float* p, short8v& q0, short8v& q1, short8v& q2) {
  float4 v0 = *(const float4*)(p);
  float4 v1 = *(const float4*)(p + 4);
  float f[8] = {v0.x, v0.y, v0.z, v0.w, v1.x, v1.y, v1.z, v1.w};
#pragma unroll
  for (int e = 0; e < 8; ++e) {
    float x = f[e];
    unsigned short hb = f2bf(x);
    float xr = x - bf2f(hb);
    unsigned short mb = f2bf(xr);
    float x2 = xr - bf2f(mb);
    q0[e] = (short)hb;
    q1[e] = (short)mb;
    q2[e] = (short)f2bf(x2);
  }
}

// ---------------- fused GRU, fp32-accurate via 3-plane bf16 MFMA ----------------
// Block: 128 rows x 32 gate-cols; 4 waves of 32 rows (rt=2), ct=2.
// Per arr (0:Agg/Wf, 1:H/Whh): split A once into 3 planes (regs);
//   pass1 stages {Wh,Wm} -> 5 products (AhWh,AmWh,AlWh,AhWm,AmWm)
//   pass2 stages {Wl}    -> 1 product  (AhWl)
// LDS XOR-swizzled (chunk ^ row&7), written and read with the same involution.
__global__ __launch_bounds__(256, 2) void gru_mfma3(
    const float* __restrict__ Agg, const float* __restrict__ H,
    const unsigned short* __restrict__ Wp,   // [3][768][128] bf16 bits
    const float* __restrict__ bih, const float* __restrict__ bhh,
    const float* __restrict__ u, const int* __restrict__ deg,
    float* __restrict__ Hout, int N, int do_relu)
{
  __shared__ short sB[2][96 * DD];  // 2 x 24KB, 96 rows (3 gates x 32 cols) x 128 k
  const int TOT = 6 * DD * DD;
  const int tid = threadIdx.x;
  const int wid = tid >> 6;
  const int lane = tid & 63;
  const int lrow = lane & 15;
  const int hi = lane >> 4;        // 0..3
  const int lk = hi * 8;           // k offset (shorts)
  const int rowBase = blockIdx.x * 128 + wid * 32;
  const int j0 = blockIdx.y * 32;

  floatx4 acc[6][2][2];
#pragma unroll
  for (int g = 0; g < 6; ++g)
#pragma unroll
    for (int ct = 0; ct < 2; ++ct)
#pragma unroll
      for (int rt = 0; rt < 2; ++rt) acc[g][ct][rt] = (floatx4){0.f, 0.f, 0.f, 0.f};

  int r0 = rowBase + lrow;       if (r0 >= N) r0 = N - 1;
  int r1 = rowBase + 16 + lrow;  if (r1 >= N) r1 = N - 1;

  // staging mapping: ch = tid + i*256 (i<6) per buffer; row=ch>>4, chunk=ch&15
  int s_row[6], s_cnk[6];
  size_t s_grow[6];
#pragma unroll
  for (int i = 0; i < 6; ++i) {
    int ch = tid + i * 256;
    s_row[i] = ch >> 4;
    s_cnk[i] = ch & 15;
    s_grow[i] = (size_t)((s_row[i] >> 5) * DD + j0 + (s_row[i] & 31));
  }

  short8v wreg[12];
  // preload arr0 Wh(plane0) + Wm(plane1)
#pragma unroll
  for (int i = 0; i < 6; ++i) {
    wreg[i]     = *(const short8v*)(Wp + 0 * TOT + s_grow[i] * DD + s_cnk[i] * 8);
    wreg[6 + i] = *(const short8v*)(Wp + 1 * TOT + s_grow[i] * DD + s_cnk[i] * 8);
  }

  // split arr0 A (= Agg) into planes
  short8v frag[3][4][2];   // [plane][kc][rt]
#pragma unroll
  for (int kc = 0; kc < 4; ++kc) {
    split8(Agg + (size_t)r0 * DD + kc * 32 + lk, frag[0][kc][0], frag[1][kc][0], frag[2][kc][0]);
    split8(Agg + (size_t)r1 * DD + kc * 32 + lk, frag[0][kc][1], frag[1][kc][1], frag[2][kc][1]);
  }

#pragma unroll
  for (int arr = 0; arr < 2; ++arr) {
    const size_t gbase = (size_t)arr * 384 * DD;
    if (arr > 0) __syncthreads();    // prior pass2 readers done
    // stage Wh -> sB[0], Wm -> sB[1] (swizzled)
#pragma unroll
    for (int i = 0; i < 6; ++i) {
      int off = s_row[i] * DD + (s_cnk[i] ^ (s_row[i] & 7)) * 8;
      *(short8v*)(&sB[0][off]) = wreg[i];
      *(short8v*)(&sB[1][off]) = wreg[6 + i];
    }
    // prefetch Wl (plane2) of this arr
#pragma unroll
    for (int i = 0; i < 6; ++i)
      wreg[i] = *(const short8v*)(Wp + 2 * TOT + gbase + s_grow[i] * DD + s_cnk[i] * 8);
    __syncthreads();

    // pass1: 5 products
#pragma unroll
    for (int kc = 0; kc < 4; ++kc) {
#pragma unroll
      for (int gl = 0; gl < 3; ++gl) {
#pragma unroll
        for (int ct = 0; ct < 2; ++ct) {
          int lr = gl * 32 + ct * 16 + lrow;
          int off = lr * DD + ((kc * 4 + hi) ^ (lr & 7)) * 8;
          short8v bh = *(const short8v*)(&sB[0][off]);
#pragma unroll
          for (int rt = 0; rt < 2; ++rt) {
            acc[arr * 3 + gl][ct][rt] = __builtin_amdgcn_mfma_f32_16x16x32_bf16(
                frag[0][kc][rt], bh, acc[arr * 3 + gl][ct][rt], 0, 0, 0);
            acc[arr * 3 + gl][ct][rt] = __builtin_amdgcn_mfma_f32_16x16x32_bf16(
                frag[1][kc][rt], bh, acc[arr * 3 + gl][ct][rt], 0, 0, 0);
            acc[arr * 3 + gl][ct][rt] = __builtin_amdgcn_mfma_f32_16x16x32_bf16(
                frag[2][kc][rt], bh, acc[arr * 3 + gl][ct][rt], 0, 0, 0);
          }
          short8v bm = *(const short8v*)(&sB[1][off]);
#pragma unroll
          for (int rt = 0; rt < 2; ++rt) {
            acc[arr * 3 + gl][ct][rt] = __builtin_amdgcn_mfma_f32_16x16x32_bf16(
                frag[0][kc][rt], bm, acc[arr * 3 + gl][ct][rt], 0, 0, 0);
            acc[arr * 3 + gl][ct][rt] = __builtin_amdgcn_mfma_f32_16x16x32_bf16(
                frag[1][kc][rt], bm, acc[arr * 3 + gl][ct][rt], 0, 0, 0);
          }
        }
      }
    }
    __syncthreads();

    // stage Wl -> sB[0]
#pragma unroll
    for (int i = 0; i < 6; ++i) {
      int off = s_row[i] * DD + (s_cnk[i] ^ (s_row[i] & 7)) * 8;
      *(short8v*)(&sB[0][off]) = wreg[i];
    }
    if (arr == 0) {
      // prefetch arr1 Wh + Wm
      const size_t g1 = (size_t)384 * DD;
#pragma unroll
      for (int i = 0; i < 6; ++i) {
        wreg[i]     = *(const short8v*)(Wp + 0 * TOT + g1 + s_grow[i] * DD + s_cnk[i] * 8);
        wreg[6 + i] = *(const short8v*)(Wp + 1 * TOT + g1 + s_grow[i] * DD + s_cnk[i] * 8);
      }
    }
    __syncthreads();

    // pass2: AhWl
#pragma unroll
    for (int kc = 0; kc < 4; ++kc) {
#pragma unroll
      for (int gl = 0; gl < 3; ++gl) {
#pragma unroll
        for (int ct = 0; ct < 2; ++ct) {
          int lr = gl * 32 + ct * 16 + lrow;
          int off = lr * DD + ((kc * 4 + hi) ^ (lr & 7)) * 8;
          short8v bl = *(const short8v*)(&sB[0][off]);
#pragma unroll
          for (int rt = 0; rt < 2; ++rt) {
            acc[arr * 3 + gl][ct][rt] = __builtin_amdgcn_mfma_f32_16x16x32_bf16(
                frag[0][kc][rt], bl, acc[arr * 3 + gl][ct][rt], 0, 0, 0);
          }
        }
      }
    }

    // split arr1 A (= H) after arr0's last use of frag
    if (arr == 0) {
#pragma unroll
      for (int kc = 0; kc < 4; ++kc) {
        split8(H + (size_t)r0 * DD + kc * 32 + lk, frag[0][kc][0], frag[1][kc][0], frag[2][kc][0]);
        split8(H + (size_t)r1 * DD + kc * 32 + lk, frag[0][kc][1], frag[1][kc][1], frag[2][kc][1]);
      }
    }
  }

  // epilogue. C/D layout: col = lane&15, row = (lane>>4)*4 + reg
  float bi_r[2], bi_z[2], bi_n[2], bh_r[2], bh_z[2], bh_n[2], u_r[2], u_z[2], u_n[2];
#pragma unroll
  for (int ct = 0; ct < 2; ++ct) {
    int c = j0 + ct * 16 + lrow;
    bi_r[ct] = bih[c];  bi_z[ct] = bih[DD + c];  bi_n[ct] = bih[2 * DD + c];
    bh_r[ct] = bhh[c];  bh_z[ct] = bhh[DD + c];  bh_n[ct] = bhh[2 * DD + c];
    u_r[ct]  = u[c];    u_z[ct]  = u[DD + c];    u_n[ct]  = u[2 * DD + c];
  }

#pragma unroll
  for (int rt = 0; rt < 2; ++rt) {
#pragma unroll
    for (int q = 0; q < 4; ++q) {
      int row = rowBase + rt * 16 + hi * 4 + q;
      if (row < N) {
        float dg = (float)deg[row];
#pragma unroll
        for (int ct = 0; ct < 2; ++ct) {
          int c = j0 + ct * 16 + lrow;
          float ir = acc[0][ct][rt][q] + bi_r[ct] + dg * u_r[ct];
          float iz = acc[1][ct][rt][q] + bi_z[ct] + dg * u_z[ct];
          float in = acc[2][ct][rt][q] + bi_n[ct] + dg * u_n[ct];
          float hr = acc[3][ct][rt][q] + bh_r[ct];
          float hz = acc[4][ct][rt][q] + bh_z[ct];
          float hn = acc[5][ct][rt][q] + bh_n[ct];
          float rg = sigmoid_f(ir + hr);
          float zg = sigmoid_f(iz + hz);
          float ng = tanh_f(in + rg * hn);
          float hold = H[(size_t)row * DD + c];
          float out = (1.0f - zg) * ng + zg * hold;
          if (do_relu) out = fmaxf(out, 0.0f);
          Hout[(size_t)row * DD + c] = out;
        }
      }
    }
  }
}

// out[c] = mean over rows of H[:, c]; out must be zeroed first
__global__ __launch_bounds__(256) void col_mean(
    const float* __restrict__ H, float* __restrict__ out, int N)
{
  __shared__ float s[256];
  int c = threadIdx.x & 127;
  int rg = threadIdx.x >> 7;
  float acc = 0.0f;
  for (int r = blockIdx.x * 2 + rg; r < N; r += gridDim.x * 2)
    acc += H[(size_t)r * DD + c];
  s[threadIdx.x] = acc;
  __syncthreads();
  if (threadIdx.x < 128) {
    float v = (s[threadIdx.x] + s[threadIdx.x + 128]) * (1.0f / (float)N);
    unsafeAtomicAdd(out + c, v);
  }
}

extern "C" void kernel_launch(void* const* d_in, const int* in_sizes, int n_in,
                              void* d_out, int out_size, void* d_ws, size_t ws_size,
                              hipStream_t stream) {
  const float* in_feat = (const float*)d_in[0];
  const int* src = (const int*)d_in[1];
  const int* dst = (const int*)d_in[2];
  const float* W[2]   = {(const float*)d_in[3], (const float*)d_in[9]};
  const float* bb[2]  = {(const float*)d_in[4], (const float*)d_in[10]};
  const float* Wih[2] = {(const float*)d_in[5], (const float*)d_in[11]};
  const float* Whh[2] = {(const float*)d_in[6], (const float*)d_in[12]};
  const float* bih[2] = {(const float*)d_in[7], (const float*)d_in[13]};
  const float* bhh[2] = {(const float*)d_in[8], (const float*)d_in[14]};
  const int N = in_sizes[0] / DD;
  const int E = in_sizes[1];

  const size_t nd = (size_t)N * DD;
  char* base = (char*)d_ws;
  float* hA  = (float*)base; base += nd * sizeof(float);
  float* hB  = (float*)base; base += nd * sizeof(float);
  float* agg = (float*)base; base += nd * sizeof(float);
  float* Wc32 = (float*)base; base += (size_t)3 * DD * DD * sizeof(float);
  unsigned short* Wp[2];
  Wp[0] = (unsigned short*)base; base += (size_t)3 * 6 * DD * DD * sizeof(unsigned short);
  Wp[1] = (unsigned short*)base; base += (size_t)3 * 6 * DD * DD * sizeof(unsigned short);
  float* u[2];
  u[0] = (float*)base; base += 3 * DD * sizeof(float);
  u[1] = (float*)base; base += 3 * DD * sizeof(float);
  int* deg  = (int*)base; base += (size_t)N * sizeof(int);
  int* ofs  = (int*)base; base += ((size_t)N + 1) * sizeof(int);
  int* cur  = (int*)base; base += (size_t)N * sizeof(int);
  int* eidx = (int*)base; base += (size_t)E * sizeof(int);

  // ---- CSR build ----
  hipMemsetAsync(deg, 0, (size_t)N * sizeof(int), stream);
  deg_count<<<(E + 255) / 256, 256, 0, stream>>>(dst, deg, E);
  scan_deg<<<1, 1024, 0, stream>>>(deg, ofs, cur, N);
  fill_csr<<<(E + 255) / 256, 256, 0, stream>>>(src, dst, cur, eidx, E);

  // ---- weights: fuse in fp32, split into 3 bf16 planes ----
  for (int layer = 0; layer < 2; ++layer) {
    fuse_w<<<3 * DD, 128, 0, stream>>>(Wih[layer], W[layer], Wc32);
    split_w<<<(6 * DD * DD + 255) / 256, 256, 0, stream>>>(Wc32, Whh[layer], Wp[layer]);
    fuse_u<<<3, 128, 0, stream>>>(Wih[layer], bb[layer], u[layer]);
  }

  hipMemcpyAsync(hA, in_feat, nd * sizeof(float), hipMemcpyDeviceToDevice, stream);

  float* hcur = hA;
  float* hnxt = hB;
  const int gblocks = (N + 7) / 8;
  const int mblocks = (N + 127) / 128;

  for (int layer = 0; layer < 2; ++layer) {
    for (int step_i = 0; step_i < 8; ++step_i) {
      gather_h<<<gblocks, 256, 0, stream>>>(hcur, ofs, eidx, agg, N);
      int do_relu = (layer == 0 && step_i == 7) ? 1 : 0;
      gru_mfma3<<<dim3(mblocks, 4), 256, 0, stream>>>(
          agg, hcur, Wp[layer], bih[layer], bhh[layer],
          u[layer], deg, hnxt, N, do_relu);
      float* t = hcur; hcur = hnxt; hnxt = t;
    }
  }

  hipMemsetAsync(d_out, 0, DD * sizeof(float), stream);
  col_mean<<<256, 256, 0, stream>>>(hcur, (float*)d_out, N);
}